// Round 6
// baseline (175.286 us; speedup 1.0000x reference)
//
#include <hip/hip_runtime.h>
#include <math.h>
#include <stdint.h>

// SVD++ scoring, R5: fire-and-forget gathers via global_load_lds.
// R2-R4 all pinned at ~41us with VGPR<=60: the compiler strip-mines any
// VGPR-destination gather batch to ~8 deep. global_load_lds has NO VGPR
// destination -> 16 x dwordx4 staged per wave (16KB in flight) cannot be
// strip-mined. Per instruction: 64 lanes x 16B = 4 rows land contiguous at
// ldsbase + lane*16 (global addr is per-lane; LDS dest is uniform+lane*16).
// Read-back: lds[r*64+lane] gives lane one COLUMN of row r -> acc += v*i_c
// folds the item dot directly (conflict-free, 2-way only).
// dot(u + summed/norm, i) = u·i + (summed·i)/norm -> scalar wave reductions.

#define WAVES_PER_BLOCK 4
#define CHUNK 64   // rows per staging round-trip; 16KB LDS per wave

__global__ __launch_bounds__(256) void svdpp_kernel(
    const int* __restrict__ user_ids,
    const int* __restrict__ item_ids,
    const int* __restrict__ offsets,
    const int* __restrict__ flat_implicit,
    const float* __restrict__ user_emb,
    const float* __restrict__ item_emb,
    const float* __restrict__ imp_emb,
    const float* __restrict__ user_bias,
    const float* __restrict__ item_bias,
    const float* __restrict__ global_bias,
    float* __restrict__ out,
    int B, int N)
{
    extern __shared__ float lds_all[];   // 4 waves * CHUNK*64 floats = 64KB
    const int wave = threadIdx.x >> 6;
    const int lane = threadIdx.x & 63;
    const int b = blockIdx.x * WAVES_PER_BLOCK + wave;
    if (b >= B) return;

    float* mylds = lds_all + wave * (CHUNK * 64);

    const int sub = lane >> 4;   // row within a 4-row staging instruction
    const int l16 = lane & 15;   // float4 within the 256B row

    const int start = offsets[b];
    const int end   = (b + 1 < B) ? offsets[b + 1] : N;
    const int n     = end - start;

    const int user = user_ids[b];
    const int item = item_ids[b];

    // lane's item coefficient (column = lane); reused for read-back fmacs
    const float i_c = item_emb[(size_t)item * 64 + lane];

    float a0 = 0.f, a1 = 0.f, a2 = 0.f, a3 = 0.f;

    for (int base = start; base < end; base += CHUNK) {
        // coalesced: 64 indices of this chunk, one per lane (masked -> start)
        const int ia = base + lane;
        const int my_idx = flat_implicit[(ia < end) ? ia : start];

        // stage CHUNK rows: 16 fire-and-forget dwordx4 gathers, no VGPR dest.
        // instruction d covers rows 4d..4d+3; lane fetches 16B of row 4d+sub.
        #pragma unroll
        for (int d = 0; d < CHUNK / 4; ++d) {
            const int ridx = __shfl(my_idx, 4 * d + sub, 64);
            const float* gsrc = imp_emb + (size_t)ridx * 64 + l16 * 4;
            __builtin_amdgcn_global_load_lds(
                (const __attribute__((address_space(1))) void*)(uintptr_t)gsrc,
                (__attribute__((address_space(3))) void*)(uint32_t)(uintptr_t)(mylds + d * 256),
                16, 0, 0);
        }
        __builtin_amdgcn_s_waitcnt(0);   // drain staging before read-back

        // read-back: row r, column `lane`; 4 accumulators break the fma chain
        #pragma unroll
        for (int r = 0; r < CHUNK; r += 4) {
            const float v0 = mylds[(r + 0) * 64 + lane];
            const float v1 = mylds[(r + 1) * 64 + lane];
            const float v2 = mylds[(r + 2) * 64 + lane];
            const float v3 = mylds[(r + 3) * 64 + lane];
            if (base + r + 0 < end) a0 += v0 * i_c;
            if (base + r + 1 < end) a1 += v1 * i_c;
            if (base + r + 2 < end) a2 += v2 * i_c;
            if (base + r + 3 < end) a3 += v3 * i_c;
        }
        __builtin_amdgcn_s_waitcnt(0);   // ds_reads done before next overwrite
    }

    float ds = (a0 + a1) + (a2 + a3);

    // u·i partial: one column per lane
    const float u_c = user_emb[(size_t)user * 64 + lane];
    float dui = u_c * i_c;

    #pragma unroll
    for (int off = 32; off >= 1; off >>= 1) {
        ds  += __shfl_xor(ds,  off, 64);
        dui += __shfl_xor(dui, off, 64);
    }

    if (lane == 0) {
        const float norm = (n > 0) ? sqrtf((float)n) : 1.0f;
        out[b] = dui + ds / norm + user_bias[user] + item_bias[item]
               + global_bias[0];
    }
}

extern "C" void kernel_launch(void* const* d_in, const int* in_sizes, int n_in,
                              void* d_out, int out_size, void* d_ws, size_t ws_size,
                              hipStream_t stream) {
    const int*   user_ids      = (const int*)  d_in[0];
    const int*   item_ids      = (const int*)  d_in[1];
    const int*   offsets       = (const int*)  d_in[2];
    const int*   flat_implicit = (const int*)  d_in[3];
    const float* user_emb      = (const float*)d_in[4];
    const float* item_emb      = (const float*)d_in[5];
    const float* imp_emb       = (const float*)d_in[6];
    const float* user_bias     = (const float*)d_in[7];
    const float* item_bias     = (const float*)d_in[8];
    const float* global_bias   = (const float*)d_in[9];
    float* out = (float*)d_out;

    const int B = in_sizes[0];
    const int N = in_sizes[3];

    const int grid = (B + WAVES_PER_BLOCK - 1) / WAVES_PER_BLOCK;
    const size_t lds_bytes = (size_t)WAVES_PER_BLOCK * CHUNK * 64 * sizeof(float);
    svdpp_kernel<<<grid, WAVES_PER_BLOCK * 64, lds_bytes, stream>>>(
        user_ids, item_ids, offsets, flat_implicit,
        user_emb, item_emb, imp_emb,
        user_bias, item_bias, global_bias,
        out, B, N);
}

// Round 7
// 141.091 us; speedup vs baseline: 1.2424x; 1.2424x over previous
//
#include <hip/hip_runtime.h>
#include <math.h>

// SVD++ scoring, R6: sched_barrier-enforced 16-deep gather batch.
// One 64-lane wave per batch element b. sub = lane>>4 (row group),
// l16 = lane&15 (float4 within the 256B row).
// Per 64-row super-iteration: ONE coalesced load of 64 indices -> __shfl
// distribution -> 16 float4 gathers -> __builtin_amdgcn_sched_barrier(0)
// -> masked accumulates. The barrier stops the compiler from interleaving
// accumulates between the loads (the strip-mining that pinned R2-R4 at
// VGPR<=60 / ~8 loads in flight). Compiler emits progressive vmcnt(15..0)
// before successive accumulates -> true 16KB in flight per wave.
// dot(u + summed/norm, i) = u·i + (summed·i)/norm -> scalar wave reductions.

#define WAVES_PER_BLOCK 4

#define LOADIDX(d) const int idx##d = __shfl(my_idx, 4*(d) + sub, 64);
#define LOADVAL(d) const float4 v##d = impv[(size_t)idx##d * 16 + l16];
#define ACCUM(d)                                                         \
    if (super + 4*(d) + sub < end) {                                     \
        acc.x += v##d.x; acc.y += v##d.y;                                \
        acc.z += v##d.z; acc.w += v##d.w;                                \
    }

__global__ __launch_bounds__(256, 1) void svdpp_kernel(
    const int* __restrict__ user_ids,
    const int* __restrict__ item_ids,
    const int* __restrict__ offsets,
    const int* __restrict__ flat_implicit,
    const float* __restrict__ user_emb,
    const float* __restrict__ item_emb,
    const float* __restrict__ imp_emb,
    const float* __restrict__ user_bias,
    const float* __restrict__ item_bias,
    const float* __restrict__ global_bias,
    float* __restrict__ out,
    int B, int N)
{
    const int wave = threadIdx.x >> 6;
    const int lane = threadIdx.x & 63;
    const int b = blockIdx.x * WAVES_PER_BLOCK + wave;
    if (b >= B) return;

    const int sub = lane >> 4;   // 0..3: which row this lane helps load
    const int l16 = lane & 15;   // 0..15: which float4 of the row

    const int start = offsets[b];
    const int end   = (b + 1 < B) ? offsets[b + 1] : N;
    const int n     = end - start;

    const int user = user_ids[b];
    const int item = item_ids[b];

    // item-embedding fragment for this lane's 4 columns (broadcast across subs)
    const float4 i4 = ((const float4*)(item_emb + (size_t)item * 64))[l16];

    const float4* impv = (const float4*)imp_emb;
    float4 acc = make_float4(0.f, 0.f, 0.f, 0.f);

    // 64 rows per super-iteration; sub-group `sub` handles rows
    // super + 4*d + sub, d = 0..15. Out-of-range slots read a safe index
    // (flat_implicit[start]) and are masked out of the accumulate, so all
    // 16 gathers issue unconditionally.
    for (int super = start; super < end; super += 64) {
        const int a = super + lane;
        const int my_idx = flat_implicit[(a < end) ? a : start];

        LOADIDX(0)  LOADIDX(1)  LOADIDX(2)  LOADIDX(3)
        LOADIDX(4)  LOADIDX(5)  LOADIDX(6)  LOADIDX(7)
        LOADIDX(8)  LOADIDX(9)  LOADIDX(10) LOADIDX(11)
        LOADIDX(12) LOADIDX(13) LOADIDX(14) LOADIDX(15)

        LOADVAL(0)  LOADVAL(1)  LOADVAL(2)  LOADVAL(3)
        LOADVAL(4)  LOADVAL(5)  LOADVAL(6)  LOADVAL(7)
        LOADVAL(8)  LOADVAL(9)  LOADVAL(10) LOADVAL(11)
        LOADVAL(12) LOADVAL(13) LOADVAL(14) LOADVAL(15)

        // nothing may cross: all 16 gathers issue before any accumulate
        __builtin_amdgcn_sched_barrier(0);

        ACCUM(0)  ACCUM(1)  ACCUM(2)  ACCUM(3)
        ACCUM(4)  ACCUM(5)  ACCUM(6)  ACCUM(7)
        ACCUM(8)  ACCUM(9)  ACCUM(10) ACCUM(11)
        ACCUM(12) ACCUM(13) ACCUM(14) ACCUM(15)
    }

    // partial of summed·i (reduce over all 64 lanes: subs × columns)
    float ds = acc.x * i4.x + acc.y * i4.y + acc.z * i4.z + acc.w * i4.w;

    // partial of u·i: one column per lane
    const float u_c = user_emb[(size_t)user * 64 + lane];
    const float i_c = item_emb[(size_t)item * 64 + lane];
    float dui = u_c * i_c;

    // wave-wide butterfly reduction of both scalars
    #pragma unroll
    for (int off = 32; off >= 1; off >>= 1) {
        ds  += __shfl_xor(ds,  off, 64);
        dui += __shfl_xor(dui, off, 64);
    }

    if (lane == 0) {
        const float norm = (n > 0) ? sqrtf((float)n) : 1.0f;
        out[b] = dui + ds / norm + user_bias[user] + item_bias[item]
               + global_bias[0];
    }
}

extern "C" void kernel_launch(void* const* d_in, const int* in_sizes, int n_in,
                              void* d_out, int out_size, void* d_ws, size_t ws_size,
                              hipStream_t stream) {
    const int*   user_ids      = (const int*)  d_in[0];
    const int*   item_ids      = (const int*)  d_in[1];
    const int*   offsets       = (const int*)  d_in[2];
    const int*   flat_implicit = (const int*)  d_in[3];
    const float* user_emb      = (const float*)d_in[4];
    const float* item_emb      = (const float*)d_in[5];
    const float* imp_emb       = (const float*)d_in[6];
    const float* user_bias     = (const float*)d_in[7];
    const float* item_bias     = (const float*)d_in[8];
    const float* global_bias   = (const float*)d_in[9];
    float* out = (float*)d_out;

    const int B = in_sizes[0];
    const int N = in_sizes[3];

    const int grid = (B + WAVES_PER_BLOCK - 1) / WAVES_PER_BLOCK;
    svdpp_kernel<<<grid, WAVES_PER_BLOCK * 64, 0, stream>>>(
        user_ids, item_ids, offsets, flat_implicit,
        user_emb, item_emb, imp_emb,
        user_bias, item_bias, global_bias,
        out, B, N);
}